// Round 8
// baseline (327.803 us; speedup 1.0000x reference)
//
#include <hip/hip_runtime.h>
#include <stdint.h>

// out[ch][s] = sum_{v: sp[v]==s} x[ch][ht[v]] * w[v],  ch in [0,128)
//
// R1: atomic scatter wrote 768 MB -> bin by sphere (601us).
// R2: accum f32 gather bound -> bf16 xT (516us).
// R3: scatter 8B-random writes: 95MB amp + per-vote cursor atomics (115us).
// R4 FAILED (1532us): accum latency-bound (dependent global chains).
// R5 (409us): 1024-bucket sort + LDS-staged accum.
// R6 FAILED: epilogue cross-half LDS combine raced (no store->load dep).
// R7 (318us): register shfl_xor combine. No kernel dominates.
// R8: init -> memset (relative cursors); transpose+reorder fused (co-sched);
//     accum quarter-wave dwordx4 (full 256B row/vote, 4 votes/wave-iter,
//     half the VMEM instrs, 2-stage shfl_xor(16,32) reduce).

#define S_BINS   32768
#define NBUCKET  1024        // coarse buckets = s >> 5
#define BINS     32          // fine bins per bucket
#define CAP      2048        // record slots per bucket (mean 1465, +15 sigma)
#define CHUNK    4096        // votes per reorder block
#define HT_BITS  18          // HW = 512*512 = 2^18
#define SMEM_BYTES (CHUNK*8 + CHUNK*2 + 4*NBUCKET*4 + 512*4)   // 59392

__device__ __forceinline__ unsigned bf16_rne(float f) {
    unsigned u = __float_as_uint(f);
    return (u + 0x7FFFu + ((u >> 16) & 1u)) >> 16;   // round-nearest-even
}

// Fused: blocks [0, TBLK) transpose x -> xTb; blocks [TBLK, TBLK+nblk) group
// votes by bucket and dump grouped runs. Independent work, one launch.
// xTb [HW][64] u32; word cp = bf16(ch=cp) | bf16(ch=cp+64)<<16.
// record: x = ht | (s_local<<18), y = w bits. Cursors RELATIVE (memset-zeroed).
__global__ __launch_bounds__(512) void prep_kernel(
    const float* __restrict__ x, const int* __restrict__ ht,
    const int* __restrict__ sp, const float* __restrict__ w,
    uint32_t* __restrict__ xTb, int* __restrict__ cursor,
    uint2* __restrict__ records, uint2* __restrict__ spillRec,
    int* __restrict__ spillBkt, int* __restrict__ spillCnt,
    int V, int HW, int TBLK) {
    __shared__ __align__(16) char smem[SMEM_BYTES];
    const int t = threadIdx.x;                       // 512
    if ((int)blockIdx.x < TBLK) {
        // ---- transpose tile: 64 ht x 128 ch ----
        float* tile = (float*)smem;                  // [64][129]
        const int ht0 = blockIdx.x * 64;
        const float2* x2 = (const float2*)x;
        for (int e = t; e < 128 * 32; e += 512) {    // float2 loads
            const int ch = e >> 5, hp = e & 31;
            const float2 v = x2[((size_t)ch * HW + ht0) / 2 + hp];
            tile[(2 * hp) * 129 + ch]     = v.x;
            tile[(2 * hp + 1) * 129 + ch] = v.y;
        }
        __syncthreads();
        for (int e = t; e < 64 * 64; e += 512) {
            const int hl = e >> 6, cp = e & 63;
            const unsigned lo = bf16_rne(tile[hl * 129 + cp]);
            const unsigned hi = bf16_rne(tile[hl * 129 + cp + 64]);
            xTb[(size_t)(ht0 + hl) * 64 + cp] = lo | (hi << 16);
        }
        return;
    }
    // ---- reorder chunk ----
    uint2*    rec    = (uint2*)smem;                          // 32 KB
    uint16_t* bid    = (uint16_t*)(smem + CHUNK * 8);         // 8 KB
    int* hist   = (int*)(smem + CHUNK * 8 + CHUNK * 2);
    int* startB = hist + NBUCKET;
    int* curB   = startB + NBUCKET;
    int* gbase  = curB + NBUCKET;
    int* psum   = gbase + NBUCKET;                            // 512 ints
    const int blk = blockIdx.x - TBLK;
    const int base = blk * CHUNK, end = min(V, base + CHUNK), n = end - base;
    hist[2 * t] = 0; hist[2 * t + 1] = 0;
    __syncthreads();
    for (int v = base + t; v < end; v += 512) atomicAdd(&hist[sp[v] >> 5], 1);
    __syncthreads();
    const int l0 = hist[2 * t], l1 = hist[2 * t + 1];
    psum[t] = l0 + l1;
    __syncthreads();
    for (int off = 1; off < 512; off <<= 1) {        // scan 1024 via 512 thr
        const int add = (t >= off) ? psum[t - off] : 0;
        __syncthreads();
        psum[t] += add;
        __syncthreads();
    }
    int run = (t == 0) ? 0 : psum[t - 1];
    startB[2 * t]     = run; curB[2 * t]     = run; run += l0;
    startB[2 * t + 1] = run; curB[2 * t + 1] = run;
    if (l0) gbase[2 * t]     = atomicAdd(&cursor[2 * t],     l0);
    if (l1) gbase[2 * t + 1] = atomicAdd(&cursor[2 * t + 1], l1);
    __syncthreads();
    for (int v = base + t; v < end; v += 512) {
        const int s = sp[v];
        const int b = s >> 5, sl = s & 31;
        const int pos = atomicAdd(&curB[b], 1);
        rec[pos] = make_uint2((unsigned)ht[v] | ((unsigned)sl << HT_BITS),
                              __float_as_uint(w[v]));
        bid[pos] = (uint16_t)b;
    }
    __syncthreads();
    for (int i = t; i < n; i += 512) {
        const int b = bid[i];
        const int slot = gbase[b] + (i - startB[b]);  // relative to bucket
        if (slot < CAP) {
            records[(size_t)b * CAP + slot] = rec[i];
        } else {                                      // overflow: spill (cold)
            const int pos = atomicAdd(spillCnt, 1);
            spillRec[pos] = rec[i];
            spillBkt[pos] = b;
        }
    }
}

// One block per bucket, 8 waves x 64 lanes. Records staged+fine-sorted in LDS
// (32 bins); wave owns 4 bins; QUARTER-WAVE (16 lanes) processes one vote via
// dwordx4 (full 256B row); 8-deep unroll x 4 votes = 32 loads in flight/wave;
// 2-stage __shfl_xor(16,32) register reduce; quarter0 writes epilogue.
__global__ __launch_bounds__(512) void accum_kernel(
    const uint32_t* __restrict__ xTb, const uint2* __restrict__ records,
    const int* __restrict__ cursor, float* __restrict__ out) {
    __shared__ uint2 sorted[CAP];                        // 16 KB
    __shared__ __align__(16) char rawbuf[BINS * 129 * 4];// 16.5 KB raw/epilogue
    __shared__ int hist[BINS], off[BINS + 1], cur[BINS];
    uint2* raw = (uint2*)rawbuf;
    const uint4* xTb4 = (const uint4*)xTb;               // [HW][16] uint4 rows
    const int bkt = blockIdx.x, t = threadIdx.x;
    const int lane = t & 63, wv = t >> 6;                // 8 waves
    const int q = lane >> 4, ql = lane & 15;             // quarter id / lane
    const int n = min(cursor[bkt], CAP);
    const int rbase = bkt * CAP;
    float a[4][8];
#pragma unroll
    for (int i = 0; i < 4; ++i)
#pragma unroll
        for (int j = 0; j < 8; ++j) a[i][j] = 0.f;

    if (t < BINS) hist[t] = 0;
    __syncthreads();
    for (int i = t; i < n; i += 512) {                   // stage + histogram
        const uint2 r = records[rbase + i];
        raw[i] = r;
        atomicAdd(&hist[(r.x >> HT_BITS) & 31], 1);
    }
    __syncthreads();
    if (t == 0) {                                        // tiny 32-entry scan
        int run = 0;
        for (int j = 0; j < BINS; ++j) { off[j] = run; cur[j] = run; run += hist[j]; }
        off[BINS] = run;
    }
    __syncthreads();
    for (int i = t; i < n; i += 512) {                   // place sorted
        const uint2 r = raw[i];
        const int pos = atomicAdd(&cur[(r.x >> HT_BITS) & 31], 1);
        sorted[pos] = r;
    }
    __syncthreads();
#pragma unroll
    for (int bb = 0; bb < 4; ++bb) {                     // wave-uniform control
        const int f = wv * 4 + bb;
        const int s0 = off[f], s1 = off[f + 1];
        for (int k = s0; k < s1; k += 32) {              // 8-deep x 4 votes
#pragma unroll
            for (int u = 0; u < 8; ++u) {
                const int kk = k + 4 * u + q;
                if (kk < s1) {
                    const uint2 r = sorted[kk];          // 4-addr LDS broadcast
                    const uint4 g = xTb4[(size_t)(r.x & 0x3FFFF) * 16 + ql];
                    const float wt = __uint_as_float(r.y);
                    a[bb][0] += __uint_as_float(g.x << 16) * wt;
                    a[bb][4] += __uint_as_float(g.x & 0xFFFF0000u) * wt;
                    a[bb][1] += __uint_as_float(g.y << 16) * wt;
                    a[bb][5] += __uint_as_float(g.y & 0xFFFF0000u) * wt;
                    a[bb][2] += __uint_as_float(g.z << 16) * wt;
                    a[bb][6] += __uint_as_float(g.z & 0xFFFF0000u) * wt;
                    a[bb][3] += __uint_as_float(g.w << 16) * wt;
                    a[bb][7] += __uint_as_float(g.w & 0xFFFF0000u) * wt;
                }
            }
        }
    }
    // combine quarters in registers (race-free, full wave)
#pragma unroll
    for (int bb = 0; bb < 4; ++bb)
#pragma unroll
        for (int j = 0; j < 8; ++j) {
            a[bb][j] += __shfl_xor(a[bb][j], 16);
            a[bb][j] += __shfl_xor(a[bb][j], 32);
        }
    __syncthreads();                                     // before LDS reuse
    // epilogue: quarter0 lanes hold full sums for ch {4ql+i, 4ql+64+i}
    float* epi = (float*)rawbuf;                         // [32][129]
    if (q == 0) {
#pragma unroll
        for (int bb = 0; bb < 4; ++bb) {
            const int f = wv * 4 + bb;
#pragma unroll
            for (int i = 0; i < 4; ++i) {
                epi[f * 129 + 4 * ql + i]      = a[bb][i];
                epi[f * 129 + 4 * ql + 64 + i] = a[bb][4 + i];
            }
        }
    }
    __syncthreads();
    for (int i = t; i < 128 * BINS; i += 512) {
        const int ch = i >> 5, bin = i & 31;
        out[(size_t)ch * S_BINS + bkt * BINS + bin] = epi[bin * 129 + ch];
    }
}

// Spilled votes (cold): atomicAdd into out on top of accum's exact sums.
__global__ void spill_kernel(const uint32_t* __restrict__ xTb,
                             const uint2* __restrict__ spillRec,
                             const int* __restrict__ spillBkt,
                             const int* __restrict__ spillCnt,
                             float* __restrict__ out) {
    const int cnt = *spillCnt;
    const long total = (long)cnt * 64;
    for (long u = (long)blockIdx.x * blockDim.x + threadIdx.x; u < total;
         u += (long)gridDim.x * blockDim.x) {
        const int i  = (int)(u >> 6);
        const int cp = (int)(u & 63);
        const uint2 r = spillRec[i];
        const int s = (spillBkt[i] << 5) | ((r.x >> HT_BITS) & 31);
        const uint32_t g = xTb[(size_t)(r.x & 0x3FFFF) * 64 + cp];
        const float wt = __uint_as_float(r.y);
        atomicAdd(&out[(size_t)cp * S_BINS + s],
                  __uint_as_float(g << 16) * wt);
        atomicAdd(&out[(size_t)(cp + 64) * S_BINS + s],
                  __uint_as_float(g & 0xFFFF0000u) * wt);
    }
}

// ---- fallback (direct atomic, any shape) ----
__global__ void direct_kernel(const float* __restrict__ x,
                              const int* __restrict__ ht_idx,
                              const int* __restrict__ sp_idx,
                              const float* __restrict__ weight,
                              float* __restrict__ out, int V, int HW, int S,
                              int CH) {
    const int v = blockIdx.x * 2 + (threadIdx.x >> 7);
    if (v >= V) return;
    const int ch = threadIdx.x & 127;
    if (ch >= CH) return;
    atomicAdd(&out[(size_t)ch * S + sp_idx[v]],
              x[(size_t)ch * HW + ht_idx[v]] * weight[v]);
}

extern "C" void kernel_launch(void* const* d_in, const int* in_sizes, int n_in,
                              void* d_out, int out_size, void* d_ws, size_t ws_size,
                              hipStream_t stream) {
    const float* x  = (const float*)d_in[0];
    const int*   ht = (const int*)d_in[1];
    const int*   sp = (const int*)d_in[2];
    const float* w  = (const float*)d_in[3];
    float* out = (float*)d_out;

    const int HW = 512 * 512;
    const int CH = in_sizes[0] / HW;          // 128
    const int S  = out_size / CH;             // 32768
    const int V  = in_sizes[1];               // 1.5M
    const int nblk = (V + CHUNK - 1) / CHUNK; // 367
    const int TBLK = HW / 64;                 // 4096 transpose tiles

    const size_t xTb_bytes = (size_t)CH * HW * sizeof(uint16_t);    // 64 MB
    const size_t rec_bytes = (size_t)NBUCKET * CAP * sizeof(uint2); // 16 MB
    const size_t spr_bytes = (size_t)V * sizeof(uint2);             // 12 MB
    const size_t spb_bytes = (size_t)V * sizeof(int);               // 6 MB
    const size_t cur_bytes = (size_t)NBUCKET * sizeof(int);
    const size_t cnt_bytes = 64;
    const size_t need = xTb_bytes + rec_bytes + spr_bytes + spb_bytes +
                        cur_bytes + cnt_bytes;

    if (CH == 128 && S == S_BINS && HW == (1 << HT_BITS) && ws_size >= need) {
        char* p = (char*)d_ws;
        uint32_t* xTb  = (uint32_t*)p;  p += xTb_bytes;
        uint2* records = (uint2*)p;     p += rec_bytes;
        uint2* spillRec= (uint2*)p;     p += spr_bytes;
        int* spillBkt  = (int*)p;       p += spb_bytes;
        int* cursor    = (int*)p;       p += cur_bytes;   // cursor+spillCnt
        int* spillCnt  = (int*)p;                         //   contiguous

        hipMemsetAsync(cursor, 0, cur_bytes + sizeof(int), stream);
        prep_kernel<<<TBLK + nblk, 512, 0, stream>>>(
            x, ht, sp, w, xTb, cursor, records, spillRec, spillBkt, spillCnt,
            V, HW, TBLK);
        accum_kernel<<<NBUCKET, 512, 0, stream>>>(xTb, records, cursor, out);
        spill_kernel<<<256, 256, 0, stream>>>(xTb, spillRec, spillBkt, spillCnt,
                                              out);
    } else {
        hipMemsetAsync(out, 0, (size_t)out_size * sizeof(float), stream);
        direct_kernel<<<(V + 1) / 2, 256, 0, stream>>>(x, ht, sp, w, out, V, HW,
                                                       S, CH);
    }
}